// Round 11
// baseline (181.330 us; speedup 1.0000x reference)
//
#include <hip/hip_runtime.h>

#define BSZ 2
#define SEQ 2048
#define CH  1024
#define NH  16
#define HD  64
#define LOG2E 1.4426950408889634f
#define MASKC (-14426.950408889634f)   /* -10000 * log2(e) */

typedef short  bf16x8 __attribute__((ext_vector_type(8)));
typedef short  bf16x4 __attribute__((ext_vector_type(4)));
typedef float  f32x4  __attribute__((ext_vector_type(4)));

__device__ __forceinline__ short f2bf(float f) {
    union { float f; unsigned u; } v; v.f = f;
    unsigned r = v.u + 0x7FFFu + ((v.u >> 16) & 1u);   // RNE
    return (short)(r >> 16);
}
// Single-instruction exp2 THROUGH THE COMPILER (TRANS-op result hazard needs
// a compiler-inserted wait state; bare inline asm broke correctness earlier).
__device__ __forceinline__ float exp2_hw(float x) {
#if __has_builtin(__builtin_amdgcn_exp2f)
    return __builtin_amdgcn_exp2f(x);
#else
    float r;
    asm volatile("v_exp_f32 %0, %1\n\ts_nop 1" : "=v"(r) : "v"(x));
    return r;
#endif
}

// Pack 4 f32 -> bf16x4 via v_cvt_pk_bf16_f32 (RNE + pack in ONE instr).
// Verified on-hardware in R9: VALUBusy 35->30.5%, attn 61->59 µs, absmax
// unchanged.  s_nop 1 guards the TRANS(v_exp)->asm hazard; early-clobber.
__device__ __forceinline__ bf16x4 pack4_rne(float p0, float p1, float p2, float p3) {
    unsigned lo, hi;
    asm("s_nop 1\n\t"
        "v_cvt_pk_bf16_f32 %0, %2, %3\n\t"
        "v_cvt_pk_bf16_f32 %1, %4, %5"
        : "=&v"(lo), "=&v"(hi)
        : "v"(p0), "v"(p1), "v"(p2), "v"(p3));
    union { unsigned u[2]; bf16x4 v; } r;
    r.u[0] = lo; r.u[1] = hi;
    return r.v;
}

// 16x16x16 bf16 MFMA (K=16): C/D layout of a 16x16 MFMA equals this op's
// B-operand layout, which is what makes register-resident P^T possible.
#if __has_builtin(__builtin_amdgcn_mfma_f32_16x16x16bf16_1k)
__device__ __forceinline__ f32x4 mfma16x16x16(bf16x4 a, bf16x4 b, f32x4 c) {
    return __builtin_amdgcn_mfma_f32_16x16x16bf16_1k(a, b, c, 0, 0, 0);
}
#else
__device__ __forceinline__ f32x4 mfma16x16x16(bf16x4 a, bf16x4 b, f32x4 c) {
    f32x4 d;
    asm("v_mfma_f32_16x16x16_bf16 %0, %1, %2, %3"
        : "=v"(d) : "v"(a), "v"(b), "v"(c));
    return d;
}
#endif

// Async global->LDS, 16 B/lane (ladder step 3: 517->874 TF at 128² tile).
// LDS dest = wave-uniform base + lane*16 (linear); global src per-lane.
__device__ __forceinline__ void gload16(const short* g, short* lbase, int lane) {
#if __has_builtin(__builtin_amdgcn_global_load_lds)
    (void)lane;
    __builtin_amdgcn_global_load_lds(
        (const __attribute__((address_space(1))) void*)g,
        (__attribute__((address_space(3))) void*)lbase, 16, 0, 0);
#else
    *(bf16x8*)(lbase + lane * 8) = *(const bf16x8*)g;
#endif
}

// ---------------------------------------------------------------------------
// PREP kernel (R11: vtr transpose moved into proj kernel for overlap):
//   blocks [0, 2048)     : query fp32 -> qc bf16
//   blocks [2048, 4096)  : key   fp32 -> kc bf16
//   blocks [4096, 4352)  : Wq [k][n] -> wtq [n][k] bf16
//   blocks [4352, 4608)  : Wk [k][n] -> wtk [n][k] bf16
// ---------------------------------------------------------------------------
__global__ __launch_bounds__(256) void prep(
    const float* __restrict__ query, const float* __restrict__ key,
    const float* __restrict__ Wq, const float* __restrict__ Wk,
    short* __restrict__ qc, short* __restrict__ kc,
    short* __restrict__ wtq, short* __restrict__ wtk)
{
    __shared__ float tile[64][65];
    const int bid = blockIdx.x;
    const int tid = threadIdx.x;

    if (bid < 4096) {
        // ---- straight cast, 2048 elements per block ----
        const float* s = (bid < 2048) ? query : key;
        short*       d = (bid < 2048) ? qc : kc;
        long i = ((long)(bid & 2047) * 256 + tid) * 8;
        float4 v0 = *(const float4*)&s[i];
        float4 v1 = *(const float4*)&s[i + 4];
        bf16x8 o;
        o[0] = f2bf(v0.x); o[1] = f2bf(v0.y); o[2] = f2bf(v0.z); o[3] = f2bf(v0.w);
        o[4] = f2bf(v1.x); o[5] = f2bf(v1.y); o[6] = f2bf(v1.z); o[7] = f2bf(v1.w);
        *(bf16x8*)&d[i] = o;
        return;
    }

    // ---- 64x64 tiled transpose + cast (weights only) ----
    int t = bid - 4096;               // 0..511
    const float* s = (t < 256) ? Wq : Wk;
    short*       d = (t < 256) ? wtq : wtk;
    t &= 255;
    const int r0 = (t >> 4) * 64;     // k
    const int c0 = (t & 15) * 64;     // n

    const int r  = tid >> 2;          // 0..63
    const int c4 = (tid & 3) << 4;    // 0,16,32,48
    #pragma unroll
    for (int i = 0; i < 16; i += 4) {
        float4 v = *(const float4*)&s[(long)(r0 + r) * CH + c0 + c4 + i];
        tile[r][c4 + i + 0] = v.x;
        tile[r][c4 + i + 1] = v.y;
        tile[r][c4 + i + 2] = v.z;
        tile[r][c4 + i + 3] = v.w;
    }
    __syncthreads();
    bf16x8 o0, o1;
    #pragma unroll
    for (int i = 0; i < 8; i++) o0[i] = f2bf(tile[c4 + i][r]);
    #pragma unroll
    for (int i = 0; i < 8; i++) o1[i] = f2bf(tile[c4 + 8 + i][r]);
    *(bf16x8*)&d[(long)(c0 + r) * CH + r0 + c4 + 0] = o0;
    *(bf16x8*)&d[(long)(c0 + r) * CH + r0 + c4 + 8] = o1;
}

// ---------------------------------------------------------------------------
// Fused Q+K projection GEMM + V^T transpose (R11).
//   blocks [0,512)    : GEMM, XCD-swizzled.  STAGING NOW global_load_lds
//     width-16 (ladder step 3: +69% over reg staging at this exact tile).
//     Linear [128][64] LDS (gload_lds needs linear dest; m97 precedent),
//     64 KB total -> 2 blocks/CU.  One barrier/iter; prefetch buf^1 then
//     compute buf (m97 pattern; barrier's vmcnt(0) drain covers the loads).
//   blocks [512,1536) : key [b][s][h*64+d] -> vtr [b*h][d][s] transpose.
//     Reads only the raw key input (no prep dependency) -> this memory-
//     bound work overlaps the compute-bound GEMM blocks.
// ---------------------------------------------------------------------------
__global__ __launch_bounds__(256, 2) void proj_mfma(
    const short* __restrict__ Xq, const short* __restrict__ Xk,
    const short* __restrict__ Wtq, const short* __restrict__ Wtk,
    const float* __restrict__ bq_, const float* __restrict__ bk_,
    short* __restrict__ Yq, short* __restrict__ Yk,
    const float* __restrict__ key, short* __restrict__ vtr)
{
    __shared__ short At[2][128 * 64];   // 32 KB
    __shared__ short Bt[2][128 * 64];   // 32 KB

    const int bid = blockIdx.x;
    const int tid = threadIdx.x;

    if (bid >= 512) {
        // ---- V^T transpose (moved from prep; reuses At as scratch) ----
        float (*tile)[65] = (float (*)[65])&At[0][0];   // 16.6 KB < 32 KB
        int t = bid - 512;            // 0..1023
        int z = t >> 5;               // b*16+h
        int sy = t & 31;              // s tile
        const float* s = key + (long)(z >> 4) * SEQ * CH + (long)(z & 15) * HD;
        short* d = vtr + (long)z * HD * SEQ;
        const int r0 = sy * 64;
        const int r  = tid >> 2;
        const int c4 = (tid & 3) << 4;
        #pragma unroll
        for (int i = 0; i < 16; i += 4) {
            float4 v = *(const float4*)&s[(long)(r0 + r) * CH + c4 + i];
            tile[r][c4 + i + 0] = v.x;
            tile[r][c4 + i + 1] = v.y;
            tile[r][c4 + i + 2] = v.z;
            tile[r][c4 + i + 3] = v.w;
        }
        __syncthreads();
        bf16x8 o0, o1;
        #pragma unroll
        for (int i = 0; i < 8; i++) o0[i] = f2bf(tile[c4 + i][r]);
        #pragma unroll
        for (int i = 0; i < 8; i++) o1[i] = f2bf(tile[c4 + 8 + i][r]);
        *(bf16x8*)&d[(long)r * SEQ + r0 + c4 + 0] = o0;
        *(bf16x8*)&d[(long)r * SEQ + r0 + c4 + 8] = o1;
        return;
    }

    // ---- GEMM path: XCD swizzle (pair = m,z group on fixed XCD) ----
    const int g    = bid >> 3, xcd = bid & 7;
    const int pair = ((g >> 3) << 3) | xcd;   // 0..63 = y*2+z
    const int xt   = g & 7;                   // n-tile 0..7
    const int yy   = pair >> 1;               // m-tile 0..31
    const int zz   = pair & 1;                // operand set

    const short* X    = zz ? Xk  : Xq;
    const short* Wt   = zz ? Wtk : Wtq;
    const float* bias = zz ? bk_ : bq_;
    short*       Y    = zz ? Yk  : Yq;
    const float scale = zz ? 1.0f : (0.125f * LOG2E);  // fold 1/sqrt(D)*log2e into Q

    const int lane = tid & 63, w = tid >> 6;
    const int quad = lane >> 4, t16 = lane & 15;
    const int m0 = yy * 128, n0 = xt * 128;

    f32x4 acc[4][4];
    #pragma unroll
    for (int i = 0; i < 4; i++)
        #pragma unroll
        for (int j = 0; j < 4; j++)
            acc[i][j] = (f32x4){0.f, 0.f, 0.f, 0.f};

    const int M0 = (w >> 1) * 64, N0 = (w & 1) * 64;
    const int NIT = CH / 64;

    // per-lane global src for gload_lds: lane l -> row (l>>3), 16B chunk (l&7)
    const int lrow = lane >> 3;          // 0..7
    const int lcol = (lane & 7) * 8;     // shorts
    const short* ga = &X [(long)(m0 + w * 32 + lrow) * CH + lcol];
    const short* gb = &Wt[(long)(n0 + w * 32 + lrow) * CH + lcol];

    // stage 64-k tile `ko` into buffer `buf`: 4 A + 4 B gloads per wave
    // (each covers 8 rows x 128 B = 1024 B, linearly at base+lane*16)
    auto stage = [&](int buf, int ko) {
        #pragma unroll
        for (int j = 0; j < 4; j++) {
            gload16(ga + (long)(j * 8) * CH + ko, &At[buf][(w * 32 + j * 8) * 64], lane);
            gload16(gb + (long)(j * 8) * CH + ko, &Bt[buf][(w * 32 + j * 8) * 64], lane);
        }
    };

    stage(0, 0);
    __syncthreads();                      // drains vmcnt: buf0 ready

    for (int it = 0; it < NIT; it++) {
        const int buf = it & 1;
        if (it + 1 < NIT)
            stage(buf ^ 1, (it + 1) * 64);   // in flight across this compute

        #pragma unroll
        for (int kk = 0; kk < 2; kk++) {
            bf16x8 af[4], bw[4];
            #pragma unroll
            for (int im = 0; im < 4; im++)
                af[im] = *(bf16x8*)&At[buf][(M0 + 16 * im + t16) * 64 + kk * 32 + quad * 8];
            #pragma unroll
            for (int jn = 0; jn < 4; jn++)
                bw[jn] = *(bf16x8*)&Bt[buf][(N0 + 16 * jn + t16) * 64 + kk * 32 + quad * 8];
            #pragma unroll
            for (int im = 0; im < 4; im++)
                #pragma unroll
                for (int jn = 0; jn < 4; jn++)
                    acc[im][jn] = __builtin_amdgcn_mfma_f32_16x16x32_bf16(
                        af[im], bw[jn], acc[im][jn], 0, 0, 0);
        }
        __syncthreads();                  // vmcnt(0)+barrier: buf^1 complete
    }

    #pragma unroll
    for (int jn = 0; jn < 4; jn++) {
        float bs = bias[n0 + N0 + 16 * jn + t16];
        #pragma unroll
        for (int im = 0; im < 4; im++)
            #pragma unroll
            for (int reg = 0; reg < 4; reg++) {
                float y = (acc[im][jn][reg] + bs) * scale;
                Y[(long)(m0 + M0 + 16 * im + 4 * quad + reg) * (NH * HD)
                  + n0 + N0 + 16 * jn + t16] = f2bf(y);
            }
    }
}

// ---------------------------------------------------------------------------
// Flash attention — UNCHANGED from R10 (best verified: 58.2 µs).
// TRANSPOSED-SCORE form, register-resident P; KBLK=128, sub-tile QK
// interleave; cvt_pk packing; LDS-staged K/V (R6/R7: direct-global loads get
// sunk by the allocator); XCD swizzle; LDS mask; setprio.
// ---------------------------------------------------------------------------
__global__ __launch_bounds__(256, 2) void attn_mfma(
    const short* __restrict__ qp,    // [B*S][1024] bf16, pre-scaled 0.125*log2e
    const short* __restrict__ kp,    // [B*S][1024] bf16
    const short* __restrict__ vt,    // [B*H][64][S] bf16 (V transposed)
    const int*   __restrict__ amask, // [B][S] 0/1
    float* __restrict__ out)         // [B][S][H][D] fp32
{
    __shared__ short Kt[2][128 * 72];   // [key][d]   (36 KB)
    __shared__ short Vt[2][64 * 136];   // [d][key]   (34 KB)
    __shared__ float Msk[SEQ];          // mask addend (8 KB)

    // XCD swizzle: bid -> (hb on fixed XCD, q-tile)
    const int bid = blockIdx.x;            // 0..511
    const int g   = bid >> 3, xcd = bid & 7;
    const int hb  = ((g >> 4) << 3) | xcd; // 0..31 = b*16+h, fixed XCD per hb
    const int qt  = g & 15;                // q-tile 0..15

    const int qt0 = qt * 128;
    const int h   = hb & 15;
    const int b   = hb >> 4;
    const int tid = threadIdx.x;
    const int lane = tid & 63, w = tid >> 6;
    const int quad = lane >> 4, t16 = lane & 15;

    // ---- mask row -> LDS float addend, once ----
    {
        int4 a0 = *(const int4*)&amask[b * SEQ + tid * 8];
        int4 a1 = *(const int4*)&amask[b * SEQ + tid * 8 + 4];
        float4 f0 = {a0.x ? 0.f : MASKC, a0.y ? 0.f : MASKC,
                     a0.z ? 0.f : MASKC, a0.w ? 0.f : MASKC};
        float4 f1 = {a1.x ? 0.f : MASKC, a1.y ? 0.f : MASKC,
                     a1.z ? 0.f : MASKC, a1.w ? 0.f : MASKC};
        *(float4*)&Msk[tid * 8]     = f0;
        *(float4*)&Msk[tid * 8 + 4] = f1;
    }

    // Q B-frags, loaded once: B[k = ds*32+quad*8+j][q = qm*16+t16]
    bf16x8 qf[2][2];
    #pragma unroll
    for (int qm = 0; qm < 2; qm++)
        #pragma unroll
        for (int ds = 0; ds < 2; ds++)
            qf[qm][ds] = *(const bf16x8*)&qp[
                (long)(b * SEQ + qt0 + w * 32 + qm * 16 + t16) * CH
                + h * HD + ds * 32 + quad * 8];

    f32x4 oa[4][2];                  // [dt][qm]: out^T [d=16dt+4quad+reg][q]
    float l_r[2];
    #pragma unroll
    for (int dt = 0; dt < 4; dt++)
        #pragma unroll
        for (int qm = 0; qm < 2; qm++)
            oa[dt][qm] = (f32x4){0.f, 0.f, 0.f, 0.f};
    l_r[0] = l_r[1] = 0.f;

    // K staging map: 128 rows x 128 B; thread -> row tid>>1, 64 B half
    const int ksrow = tid >> 1;           // 0..127
    const int kscol = (tid & 1) * 32;     // 0 / 32 (shorts)
    // V staging map: 64 rows x 256 B; thread -> row tid>>2, 64 B quarter
    const int vsrow = tid >> 2;           // 0..63
    const int vscol = (tid & 3) * 32;     // 0,32,64,96 (shorts)
    const long kbase = (long)(b * SEQ) * CH + h * HD;
    const long vbase = ((long)(b * NH + h) * HD) * SEQ;
    const int NIT = SEQ / 128;            // 16 phases

    bf16x8 kr[4], vr[4];
    // phase 0 -> regs -> buf0; phase 1 -> regs
    #pragma unroll
    for (int c = 0; c < 4; c++) {
        kr[c] = *(const bf16x8*)&kp[kbase + (long)ksrow * CH + kscol + 8 * c];
        vr[c] = *(const bf16x8*)&vt[vbase + (long)vsrow * SEQ + vscol + 8 * c];
    }
    #pragma unroll
    for (int c = 0; c < 4; c++) {
        *(bf16x8*)&Kt[0][ksrow * 72 + kscol + 8 * c] = kr[c];
        *(bf16x8*)&Vt[0][vsrow * 136 + vscol + 8 * c] = vr[c];
    }
    #pragma unroll
    for (int c = 0; c < 4; c++) {
        kr[c] = *(const bf16x8*)&kp[kbase + (long)(128 + ksrow) * CH + kscol + 8 * c];
        vr[c] = *(const bf16x8*)&vt[vbase + (long)vsrow * SEQ + 128 + vscol + 8 * c];
    }
    __syncthreads();

    for (int it = 0; it < NIT; it++) {
        const int buf = it & 1;
        const int kt0 = it * 128;

        // ---- staging: write it+1's phase, prefetch it+2's ----
        if (it + 1 < NIT) {
            #pragma unroll
            for (int c = 0; c < 4; c++) {
                *(bf16x8*)&Kt[buf ^ 1][ksrow * 72 + kscol + 8 * c] = kr[c];
                *(bf16x8*)&Vt[buf ^ 1][vsrow * 136 + vscol + 8 * c] = vr[c];
            }
            if (it + 2 < NIT) {
                const int kn = kt0 + 256;
                #pragma unroll
                for (int c = 0; c < 4; c++) {
                    kr[c] = *(const bf16x8*)&kp[kbase + (long)(kn + ksrow) * CH + kscol + 8 * c];
                    vr[c] = *(const bf16x8*)&vt[vbase + (long)vsrow * SEQ + kn + vscol + 8 * c];
                }
            }
        }

        // ---- QK for BOTH sub-tiles first (sa0 and sa1 live).  The wave
        // issues QK1's MFMAs then flows into softmax0 (independent) ->
        // matrix + VALU pipes busy simultaneously.
        f32x4 sa[2][2][4];           // [sub][qm][jt]; fully-unrolled indexing
        #pragma unroll
        for (int sub = 0; sub < 2; sub++) {
            const int ko = sub * 64;

            float4 mv4[4];
            #pragma unroll
            for (int jt = 0; jt < 4; jt++)
                mv4[jt] = *(const float4*)&Msk[kt0 + ko + jt * 16 + quad * 4];
            #pragma unroll
            for (int qm = 0; qm < 2; qm++)
                #pragma unroll
                for (int jt = 0; jt < 4; jt++)
                    sa[sub][qm][jt] = (f32x4){mv4[jt].x, mv4[jt].y, mv4[jt].z, mv4[jt].w};

            #pragma unroll
            for (int ds = 0; ds < 2; ds++) {
                bf16x8 kb[4];   // A[m=key t16][k=d]
                #pragma unroll
                for (int jt = 0; jt < 4; jt++)
                    kb[jt] = *(bf16x8*)&Kt[buf][(ko + jt * 16 + t16) * 72 + ds * 32 + quad * 8];
                __builtin_amdgcn_s_setprio(1);
                #pragma unroll
                for (int qm = 0; qm < 2; qm++)
                    #pragma unroll
                    for (int jt = 0; jt < 4; jt++)
                        sa[sub][qm][jt] = __builtin_amdgcn_mfma_f32_16x16x32_bf16(
                            kb[jt], qf[qm][ds], sa[sub][qm][jt], 0, 0, 0);
                __builtin_amdgcn_s_setprio(0);
            }
        }

        // ---- softmax + PV per sub-tile (PV MFMAs overlap next softmax) ----
        #pragma unroll
        for (int sub = 0; sub < 2; sub++) {
            const int ko = sub * 64;
            #pragma unroll
            for (int jt = 0; jt < 4; jt++) {
                bf16x4 pbq[2];
                #pragma unroll
                for (int qm = 0; qm < 2; qm++) {
                    float p0 = exp2_hw(sa[sub][qm][jt][0]);
                    float p1 = exp2_hw(sa[sub][qm][jt][1]);
                    float p2 = exp2_hw(sa[sub][qm][jt][2]);
                    float p3 = exp2_hw(sa[sub][qm][jt][3]);
                    l_r[qm] += (p0 + p1) + (p2 + p3);
                    pbq[qm] = pack4_rne(p0, p1, p2, p3);
                }
                bf16x4 va[4];   // A[m=d t16][k=key 4quad+j]
                #pragma unroll
                for (int dt = 0; dt < 4; dt++)
                    va[dt] = *(bf16x4*)&Vt[buf][(dt * 16 + t16) * 136 + ko + jt * 16 + quad * 4];
                __builtin_amdgcn_s_setprio(1);
                #pragma unroll
                for (int dt = 0; dt < 4; dt++)
                    #pragma unroll
                    for (int qm = 0; qm < 2; qm++)
                        oa[dt][qm] = mfma16x16x16(va[dt], pbq[qm], oa[dt][qm]);
                __builtin_amdgcn_s_setprio(0);
            }
        }
        __syncthreads();
    }

    // ---- epilogue: quad-reduce l, normalize, store out^T -> out ----
    #pragma unroll
    for (int qm = 0; qm < 2; qm++) {
        float l = l_r[qm];
        l += __shfl_xor(l, 16, 64);
        l += __shfl_xor(l, 32, 64);
        float inv = 1.0f / l;
        int q = qt0 + w * 32 + qm * 16 + t16;
        #pragma unroll
        for (int dt = 0; dt < 4; dt++) {
            f32x4 o = oa[dt][qm];
            float4 st = {o[0] * inv, o[1] * inv, o[2] * inv, o[3] * inv};
            *(float4*)&out[((long)(b * SEQ + q) * NH + h) * HD + dt * 16 + quad * 4] = st;
        }
    }
}

extern "C" void kernel_launch(void* const* d_in, const int* in_sizes, int n_in,
                              void* d_out, int out_size, void* d_ws, size_t ws_size,
                              hipStream_t stream) {
    const float* query = (const float*)d_in[0];
    const float* key   = (const float*)d_in[1];
    const int*   amask = (const int*)d_in[2];
    const float* Wq    = (const float*)d_in[3];
    const float* bq    = (const float*)d_in[4];
    const float* Wk    = (const float*)d_in[5];
    const float* bk    = (const float*)d_in[6];
    float* out = (float*)d_out;

    char* ws = (char*)d_ws;
    const long MB = 1024 * 1024;
    short* qc  = (short*)(ws + 0 * MB);    // query bf16 [4096][1024] (8 MB)
    short* kc  = (short*)(ws + 8 * MB);    // key   bf16 [4096][1024] (8 MB)
    short* qp  = (short*)(ws + 16 * MB);   // Q proj bf16 (8 MB)
    short* kp  = (short*)(ws + 24 * MB);   // K proj bf16 (8 MB)
    short* vtr = (short*)(ws + 32 * MB);   // V^T bf16 [B*H][64][2048] (8 MB)
    short* wtq = (short*)(ws + 40 * MB);   // Wq^T bf16 (2 MB)
    short* wtk = (short*)(ws + 42 * MB);   // Wk^T bf16 (2 MB)

    prep<<<dim3(4608), 256, 0, stream>>>(query, key, Wq, Wk, qc, kc, wtq, wtk);

    proj_mfma<<<dim3(1536), 256, 0, stream>>>(qc, kc, wtq, wtk, bq, bk, qp, kp,
                                              key, vtr);

    attn_mfma<<<dim3(512), 256, 0, stream>>>(qp, kp, vtr, amask, out);
}

// Round 12
// 168.486 us; speedup vs baseline: 1.0762x; 1.0762x over previous
//
#include <hip/hip_runtime.h>

#define BSZ 2
#define SEQ 2048
#define CH  1024
#define NH  16
#define HD  64
#define LOG2E 1.4426950408889634f
#define MASKC (-14426.950408889634f)   /* -10000 * log2(e) */

typedef short  bf16x8 __attribute__((ext_vector_type(8)));
typedef short  bf16x4 __attribute__((ext_vector_type(4)));
typedef float  f32x4  __attribute__((ext_vector_type(4)));

__device__ __forceinline__ short f2bf(float f) {
    union { float f; unsigned u; } v; v.f = f;
    unsigned r = v.u + 0x7FFFu + ((v.u >> 16) & 1u);   // RNE
    return (short)(r >> 16);
}
// Single-instruction exp2 THROUGH THE COMPILER (TRANS-op result hazard needs
// a compiler-inserted wait state; bare inline asm broke correctness earlier).
__device__ __forceinline__ float exp2_hw(float x) {
#if __has_builtin(__builtin_amdgcn_exp2f)
    return __builtin_amdgcn_exp2f(x);
#else
    float r;
    asm volatile("v_exp_f32 %0, %1\n\ts_nop 1" : "=v"(r) : "v"(x));
    return r;
#endif
}

// Pack 4 f32 -> bf16x4 via v_cvt_pk_bf16_f32 (verified R9: VALU 35->30.5%,
// attn 61->59 µs, absmax unchanged).
__device__ __forceinline__ bf16x4 pack4_rne(float p0, float p1, float p2, float p3) {
    unsigned lo, hi;
    asm("s_nop 1\n\t"
        "v_cvt_pk_bf16_f32 %0, %2, %3\n\t"
        "v_cvt_pk_bf16_f32 %1, %4, %5"
        : "=&v"(lo), "=&v"(hi)
        : "v"(p0), "v"(p1), "v"(p2), "v"(p3));
    union { unsigned u[2]; bf16x4 v; } r;
    r.u[0] = lo; r.u[1] = hi;
    return r.v;
}

#if __has_builtin(__builtin_amdgcn_mfma_f32_16x16x16bf16_1k)
__device__ __forceinline__ f32x4 mfma16x16x16(bf16x4 a, bf16x4 b, f32x4 c) {
    return __builtin_amdgcn_mfma_f32_16x16x16bf16_1k(a, b, c, 0, 0, 0);
}
#else
__device__ __forceinline__ f32x4 mfma16x16x16(bf16x4 a, bf16x4 b, f32x4 c) {
    f32x4 d;
    asm("v_mfma_f32_16x16x16_bf16 %0, %1, %2, %3"
        : "=v"(d) : "v"(a), "v"(b), "v"(c));
    return d;
}
#endif

// Async global->LDS, 16 B/lane.  LDS dest = wave-uniform base + lane*16
// (linear, HW-fixed); global src per-lane (this is where the swizzle goes).
__device__ __forceinline__ void gload16(const short* g, short* lbase, int lane) {
#if __has_builtin(__builtin_amdgcn_global_load_lds)
    (void)lane;
    __builtin_amdgcn_global_load_lds(
        (const __attribute__((address_space(1))) void*)g,
        (__attribute__((address_space(3))) void*)lbase, 16, 0, 0);
#else
    *(bf16x8*)(lbase + lane * 8) = *(const bf16x8*)g;
#endif
}

// ---------------------------------------------------------------------------
// PREP mega-kernel (R10 verified form restored — R11's vtr-in-proj fusion was
// a confounder and is reverted):
//   blocks [0, 2048)        : query fp32 -> qc bf16
//   blocks [2048, 4096)     : key   fp32 -> kc bf16
//   blocks [4096, 4352)     : Wq [k][n] -> wtq [n][k] bf16
//   blocks [4352, 4608)     : Wk [k][n] -> wtk [n][k] bf16
//   blocks [4608, 5632)     : key [b][s][h*64+d] -> vtr [b*h][d][s] bf16
// ---------------------------------------------------------------------------
__global__ __launch_bounds__(256) void prep(
    const float* __restrict__ query, const float* __restrict__ key,
    const float* __restrict__ Wq, const float* __restrict__ Wk,
    short* __restrict__ qc, short* __restrict__ kc,
    short* __restrict__ wtq, short* __restrict__ wtk,
    short* __restrict__ vtr)
{
    __shared__ float tile[64][65];
    const int bid = blockIdx.x;
    const int tid = threadIdx.x;

    if (bid < 4096) {
        const float* s = (bid < 2048) ? query : key;
        short*       d = (bid < 2048) ? qc : kc;
        long i = ((long)(bid & 2047) * 256 + tid) * 8;
        float4 v0 = *(const float4*)&s[i];
        float4 v1 = *(const float4*)&s[i + 4];
        bf16x8 o;
        o[0] = f2bf(v0.x); o[1] = f2bf(v0.y); o[2] = f2bf(v0.z); o[3] = f2bf(v0.w);
        o[4] = f2bf(v1.x); o[5] = f2bf(v1.y); o[6] = f2bf(v1.z); o[7] = f2bf(v1.w);
        *(bf16x8*)&d[i] = o;
        return;
    }

    const float* s; short* d;
    int r0, c0, srs, drs;
    if (bid < 4608) {
        int t = bid - 4096;
        s   = (t < 256) ? Wq : Wk;
        d   = (t < 256) ? wtq : wtk;
        t  &= 255;
        r0  = (t >> 4) * 64;
        c0  = (t & 15) * 64;
        srs = CH; drs = CH;
    } else {
        int t = bid - 4608;
        int z = t >> 5;
        int sy = t & 31;
        s   = key + (long)(z >> 4) * SEQ * CH + (long)(z & 15) * HD;
        d   = vtr + (long)z * HD * SEQ;
        r0  = sy * 64;
        c0  = 0;
        srs = CH; drs = SEQ;
    }

    const int r  = tid >> 2;
    const int c4 = (tid & 3) << 4;
    #pragma unroll
    for (int i = 0; i < 16; i += 4) {
        float4 v = *(const float4*)&s[(long)(r0 + r) * srs + c0 + c4 + i];
        tile[r][c4 + i + 0] = v.x;
        tile[r][c4 + i + 1] = v.y;
        tile[r][c4 + i + 2] = v.z;
        tile[r][c4 + i + 3] = v.w;
    }
    __syncthreads();
    bf16x8 o0, o1;
    #pragma unroll
    for (int i = 0; i < 8; i++) o0[i] = f2bf(tile[c4 + i][r]);
    #pragma unroll
    for (int i = 0; i < 8; i++) o1[i] = f2bf(tile[c4 + 8 + i][r]);
    *(bf16x8*)&d[(long)(c0 + r) * drs + r0 + c4 + 0] = o0;
    *(bf16x8*)&d[(long)(c0 + r) * drs + r0 + c4 + 8] = o1;
}

// ---------------------------------------------------------------------------
// Fused Q+K projection GEMM (R12): global_load_lds staging WITH the rule-21
// XOR swizzle done right.
//   R11 bug: linear [128][64-short] rows are 128 B -> every row's chunk-k in
//   the same 4-bank set -> 16-way conflict on MFMA fragment reads (16 lanes =
//   16 rows, same column).  That ate more than async staging saved.
//   Fix (m173/m201): LDS dest stays LINEAR (gload_lds HW requirement);
//   physical chunk p of row r holds logical chunk p^(r&7) (16B chunks).
//   - stage: lane l writes phys chunk (l&7) of row base+(l>>3); base rows
//     are ==0 mod 8, so its global column = ((l&7)^(l>>3))*16B — one
//     per-lane constant.
//   - read: col ^= (t16&7)*8 shorts (row&7 == t16&7 since M0,16*im ==0 mod 8).
//   Rows 0-7/8-15 spread over 8 bank-sets -> 2-way (free, m136).
//   LDS 64 KB -> 2 blocks/CU.  One barrier/iter (vmcnt(0) drain covers the
//   in-flight gloads).  XCD swizzle retained.
// ---------------------------------------------------------------------------
__global__ __launch_bounds__(256, 2) void proj_mfma(
    const short* __restrict__ Xq, const short* __restrict__ Xk,
    const short* __restrict__ Wtq, const short* __restrict__ Wtk,
    const float* __restrict__ bq_, const float* __restrict__ bk_,
    short* __restrict__ Yq, short* __restrict__ Yk)
{
    __shared__ short At[2][128 * 64];   // 32 KB
    __shared__ short Bt[2][128 * 64];   // 32 KB

    const int bid  = blockIdx.x;           // 0..511
    const int g    = bid >> 3, xcd = bid & 7;
    const int pair = ((g >> 3) << 3) | xcd;   // 0..63 = y*2+z
    const int xt   = g & 7;                   // n-tile 0..7
    const int yy   = pair >> 1;               // m-tile 0..31
    const int zz   = pair & 1;                // operand set

    const short* X    = zz ? Xk  : Xq;
    const short* Wt   = zz ? Wtk : Wtq;
    const float* bias = zz ? bk_ : bq_;
    short*       Y    = zz ? Yk  : Yq;
    const float scale = zz ? 1.0f : (0.125f * LOG2E);

    const int tid  = threadIdx.x;
    const int lane = tid & 63, w = tid >> 6;
    const int quad = lane >> 4, t16 = lane & 15;
    const int m0 = yy * 128, n0 = xt * 128;

    f32x4 acc[4][4];
    #pragma unroll
    for (int i = 0; i < 4; i++)
        #pragma unroll
        for (int j = 0; j < 4; j++)
            acc[i][j] = (f32x4){0.f, 0.f, 0.f, 0.f};

    const int M0 = (w >> 1) * 64, N0 = (w & 1) * 64;
    const int NIT = CH / 64;

    // per-lane swizzled global src: lane l -> row (l>>3), SOURCE chunk
    // (l&7)^(l>>3)  (so linear dest chunk l&7 holds logical chunk ^(row&7))
    const int lrow   = lane >> 3;                      // 0..7
    const int lcolsw = ((lane & 7) ^ lrow) * 8;        // shorts
    const short* ga = &X [(long)(m0 + w * 32 + lrow) * CH + lcolsw];
    const short* gb = &Wt[(long)(n0 + w * 32 + lrow) * CH + lcolsw];

    // stage 64-k tile `ko` into buffer `buf`: 4 A + 4 B gloads per wave,
    // each 8 rows x 128 B linear at base+lane*16.
    auto stage = [&](int buf, int ko) {
        #pragma unroll
        for (int j = 0; j < 4; j++) {
            gload16(ga + (long)(j * 8) * CH + ko, &At[buf][(w * 32 + j * 8) * 64], lane);
            gload16(gb + (long)(j * 8) * CH + ko, &Bt[buf][(w * 32 + j * 8) * 64], lane);
        }
    };

    stage(0, 0);
    __syncthreads();                      // drains vmcnt: buf0 ready

    const int rsw = (t16 & 7) * 8;        // read-side XOR (shorts)

    for (int it = 0; it < NIT; it++) {
        const int buf = it & 1;
        if (it + 1 < NIT)
            stage(buf ^ 1, (it + 1) * 64);   // in flight across this compute

        #pragma unroll
        for (int kk = 0; kk < 2; kk++) {
            bf16x8 af[4], bw[4];
            #pragma unroll
            for (int im = 0; im < 4; im++)
                af[im] = *(bf16x8*)&At[buf][(M0 + 16 * im + t16) * 64
                                            + ((kk * 32 + quad * 8) ^ rsw)];
            #pragma unroll
            for (int jn = 0; jn < 4; jn++)
                bw[jn] = *(bf16x8*)&Bt[buf][(N0 + 16 * jn + t16) * 64
                                            + ((kk * 32 + quad * 8) ^ rsw)];
            #pragma unroll
            for (int im = 0; im < 4; im++)
                #pragma unroll
                for (int jn = 0; jn < 4; jn++)
                    acc[im][jn] = __builtin_amdgcn_mfma_f32_16x16x32_bf16(
                        af[im], bw[jn], acc[im][jn], 0, 0, 0);
        }
        __syncthreads();                  // vmcnt(0)+barrier: buf^1 complete
    }

    #pragma unroll
    for (int jn = 0; jn < 4; jn++) {
        float bs = bias[n0 + N0 + 16 * jn + t16];
        #pragma unroll
        for (int im = 0; im < 4; im++)
            #pragma unroll
            for (int reg = 0; reg < 4; reg++) {
                float y = (acc[im][jn][reg] + bs) * scale;
                Y[(long)(m0 + M0 + 16 * im + 4 * quad + reg) * (NH * HD)
                  + n0 + N0 + 16 * jn + t16] = f2bf(y);
            }
    }
}

// ---------------------------------------------------------------------------
// Flash attention — UNCHANGED from R10 (best verified: 58.2 µs).
// ---------------------------------------------------------------------------
__global__ __launch_bounds__(256, 2) void attn_mfma(
    const short* __restrict__ qp,    // [B*S][1024] bf16, pre-scaled 0.125*log2e
    const short* __restrict__ kp,    // [B*S][1024] bf16
    const short* __restrict__ vt,    // [B*H][64][S] bf16 (V transposed)
    const int*   __restrict__ amask, // [B][S] 0/1
    float* __restrict__ out)         // [B][S][H][D] fp32
{
    __shared__ short Kt[2][128 * 72];   // [key][d]   (36 KB)
    __shared__ short Vt[2][64 * 136];   // [d][key]   (34 KB)
    __shared__ float Msk[SEQ];          // mask addend (8 KB)

    const int bid = blockIdx.x;            // 0..511
    const int g   = bid >> 3, xcd = bid & 7;
    const int hb  = ((g >> 4) << 3) | xcd; // 0..31 = b*16+h, fixed XCD per hb
    const int qt  = g & 15;                // q-tile 0..15

    const int qt0 = qt * 128;
    const int h   = hb & 15;
    const int b   = hb >> 4;
    const int tid = threadIdx.x;
    const int lane = tid & 63, w = tid >> 6;
    const int quad = lane >> 4, t16 = lane & 15;

    {
        int4 a0 = *(const int4*)&amask[b * SEQ + tid * 8];
        int4 a1 = *(const int4*)&amask[b * SEQ + tid * 8 + 4];
        float4 f0 = {a0.x ? 0.f : MASKC, a0.y ? 0.f : MASKC,
                     a0.z ? 0.f : MASKC, a0.w ? 0.f : MASKC};
        float4 f1 = {a1.x ? 0.f : MASKC, a1.y ? 0.f : MASKC,
                     a1.z ? 0.f : MASKC, a1.w ? 0.f : MASKC};
        *(float4*)&Msk[tid * 8]     = f0;
        *(float4*)&Msk[tid * 8 + 4] = f1;
    }

    bf16x8 qf[2][2];
    #pragma unroll
    for (int qm = 0; qm < 2; qm++)
        #pragma unroll
        for (int ds = 0; ds < 2; ds++)
            qf[qm][ds] = *(const bf16x8*)&qp[
                (long)(b * SEQ + qt0 + w * 32 + qm * 16 + t16) * CH
                + h * HD + ds * 32 + quad * 8];

    f32x4 oa[4][2];
    float l_r[2];
    #pragma unroll
    for (int dt = 0; dt < 4; dt++)
        #pragma unroll
        for (int qm = 0; qm < 2; qm++)
            oa[dt][qm] = (f32x4){0.f, 0.f, 0.f, 0.f};
    l_r[0] = l_r[1] = 0.f;

    const int ksrow = tid >> 1;
    const int kscol = (tid & 1) * 32;
    const int vsrow = tid >> 2;
    const int vscol = (tid & 3) * 32;
    const long kbase = (long)(b * SEQ) * CH + h * HD;
    const long vbase = ((long)(b * NH + h) * HD) * SEQ;
    const int NIT = SEQ / 128;

    bf16x8 kr[4], vr[4];
    #pragma unroll
    for (int c = 0; c < 4; c++) {
        kr[c] = *(const bf16x8*)&kp[kbase + (long)ksrow * CH + kscol + 8 * c];
        vr[c] = *(const bf16x8*)&vt[vbase + (long)vsrow * SEQ + vscol + 8 * c];
    }
    #pragma unroll
    for (int c = 0; c < 4; c++) {
        *(bf16x8*)&Kt[0][ksrow * 72 + kscol + 8 * c] = kr[c];
        *(bf16x8*)&Vt[0][vsrow * 136 + vscol + 8 * c] = vr[c];
    }
    #pragma unroll
    for (int c = 0; c < 4; c++) {
        kr[c] = *(const bf16x8*)&kp[kbase + (long)(128 + ksrow) * CH + kscol + 8 * c];
        vr[c] = *(const bf16x8*)&vt[vbase + (long)vsrow * SEQ + 128 + vscol + 8 * c];
    }
    __syncthreads();

    for (int it = 0; it < NIT; it++) {
        const int buf = it & 1;
        const int kt0 = it * 128;

        if (it + 1 < NIT) {
            #pragma unroll
            for (int c = 0; c < 4; c++) {
                *(bf16x8*)&Kt[buf ^ 1][ksrow * 72 + kscol + 8 * c] = kr[c];
                *(bf16x8*)&Vt[buf ^ 1][vsrow * 136 + vscol + 8 * c] = vr[c];
            }
            if (it + 2 < NIT) {
                const int kn = kt0 + 256;
                #pragma unroll
                for (int c = 0; c < 4; c++) {
                    kr[c] = *(const bf16x8*)&kp[kbase + (long)(kn + ksrow) * CH + kscol + 8 * c];
                    vr[c] = *(const bf16x8*)&vt[vbase + (long)vsrow * SEQ + kn + vscol + 8 * c];
                }
            }
        }

        f32x4 sa[2][2][4];
        #pragma unroll
        for (int sub = 0; sub < 2; sub++) {
            const int ko = sub * 64;

            float4 mv4[4];
            #pragma unroll
            for (int jt = 0; jt < 4; jt++)
                mv4[jt] = *(const float4*)&Msk[kt0 + ko + jt * 16 + quad * 4];
            #pragma unroll
            for (int qm = 0; qm < 2; qm++)
                #pragma unroll
                for (int jt = 0; jt < 4; jt++)
                    sa[sub][qm][jt] = (f32x4){mv4[jt].x, mv4[jt].y, mv4[jt].z, mv4[jt].w};

            #pragma unroll
            for (int ds = 0; ds < 2; ds++) {
                bf16x8 kb[4];
                #pragma unroll
                for (int jt = 0; jt < 4; jt++)
                    kb[jt] = *(bf16x8*)&Kt[buf][(ko + jt * 16 + t16) * 72 + ds * 32 + quad * 8];
                __builtin_amdgcn_s_setprio(1);
                #pragma unroll
                for (int qm = 0; qm < 2; qm++)
                    #pragma unroll
                    for (int jt = 0; jt < 4; jt++)
                        sa[sub][qm][jt] = __builtin_amdgcn_mfma_f32_16x16x32_bf16(
                            kb[jt], qf[qm][ds], sa[sub][qm][jt], 0, 0, 0);
                __builtin_amdgcn_s_setprio(0);
            }
        }

        #pragma unroll
        for (int sub = 0; sub < 2; sub++) {
            const int ko = sub * 64;
            #pragma unroll
            for (int jt = 0; jt < 4; jt++) {
                bf16x4 pbq[2];
                #pragma unroll
                for (int qm = 0; qm < 2; qm++) {
                    float p0 = exp2_hw(sa[sub][qm][jt][0]);
                    float p1 = exp2_hw(sa[sub][qm][jt][1]);
                    float p2 = exp2_hw(sa[sub][qm][jt][2]);
                    float p3 = exp2_hw(sa[sub][qm][jt][3]);
                    l_r[qm] += (p0 + p1) + (p2 + p3);
                    pbq[qm] = pack4_rne(p0, p1, p2, p3);
                }
                bf16x4 va[4];
                #pragma unroll
                for (int dt = 0; dt < 4; dt++)
                    va[dt] = *(bf16x4*)&Vt[buf][(dt * 16 + t16) * 136 + ko + jt * 16 + quad * 4];
                __builtin_amdgcn_s_setprio(1);
                #pragma unroll
                for (int dt = 0; dt < 4; dt++)
                    #pragma unroll
                    for (int qm = 0; qm < 2; qm++)
                        oa[dt][qm] = mfma16x16x16(va[dt], pbq[qm], oa[dt][qm]);
                __builtin_amdgcn_s_setprio(0);
            }
        }
        __syncthreads();
    }

    #pragma unroll
    for (int qm = 0; qm < 2; qm++) {
        float l = l_r[qm];
        l += __shfl_xor(l, 16, 64);
        l += __shfl_xor(l, 32, 64);
        float inv = 1.0f / l;
        int q = qt0 + w * 32 + qm * 16 + t16;
        #pragma unroll
        for (int dt = 0; dt < 4; dt++) {
            f32x4 o = oa[dt][qm];
            float4 st = {o[0] * inv, o[1] * inv, o[2] * inv, o[3] * inv};
            *(float4*)&out[((long)(b * SEQ + q) * NH + h) * HD + dt * 16 + quad * 4] = st;
        }
    }
}

extern "C" void kernel_launch(void* const* d_in, const int* in_sizes, int n_in,
                              void* d_out, int out_size, void* d_ws, size_t ws_size,
                              hipStream_t stream) {
    const float* query = (const float*)d_in[0];
    const float* key   = (const float*)d_in[1];
    const int*   amask = (const int*)d_in[2];
    const float* Wq    = (const float*)d_in[3];
    const float* bq    = (const float*)d_in[4];
    const float* Wk    = (const float*)d_in[5];
    const float* bk    = (const float*)d_in[6];
    float* out = (float*)d_out;

    char* ws = (char*)d_ws;
    const long MB = 1024 * 1024;
    short* qc  = (short*)(ws + 0 * MB);    // query bf16 [4096][1024] (8 MB)
    short* kc  = (short*)(ws + 8 * MB);    // key   bf16 [4096][1024] (8 MB)
    short* qp  = (short*)(ws + 16 * MB);   // Q proj bf16 (8 MB)
    short* kp  = (short*)(ws + 24 * MB);   // K proj bf16 (8 MB)
    short* vtr = (short*)(ws + 32 * MB);   // V^T bf16 [B*H][64][2048] (8 MB)
    short* wtq = (short*)(ws + 40 * MB);   // Wq^T bf16 (2 MB)
    short* wtk = (short*)(ws + 42 * MB);   // Wk^T bf16 (2 MB)

    prep<<<dim3(5632), 256, 0, stream>>>(query, key, Wq, Wk, qc, kc, wtq, wtk, vtr);

    proj_mfma<<<dim3(512), 256, 0, stream>>>(qc, kc, wtq, wtk, bq, bk, qp, kp);

    attn_mfma<<<dim3(512), 256, 0, stream>>>(qp, kp, vtr, amask, out);
}